// Round 15
// baseline (195.746 us; speedup 1.0000x reference)
//
#include <hip/hip_runtime.h>
#include <hip/hip_bf16.h>

#define NBANDS 31
#define CDIM 128
#define TDIM 2000
#define HDIM 512
#define MTOT 8000
#define MAXO 204
#define OPAD 224       // b2 bias padded length
#define NMTILE 504     // padded 16-row m-tiles per band
#define NMBK 63        // 128-row m-blocks per band

typedef __attribute__((ext_vector_type(8))) short short8;
typedef __attribute__((ext_vector_type(4))) float f32x4;
typedef __attribute__((ext_vector_type(4))) unsigned int u32x4;
typedef __bf16 bf16x8 __attribute__((ext_vector_type(8)));

__constant__ int d_bw[NBANDS]   = {2,3,3,3,3,3,3,3,3,3,3,8,8,8,8,8,8,8,8,8,8,8,8,16,16,16,16,16,16,16,17};
__constant__ int d_boff[NBANDS] = {0,2,5,8,11,14,17,20,23,26,29,32,40,48,56,64,72,80,88,96,104,112,120,128,144,160,176,192,208,224,240};
__constant__ int d_nn16[NBANDS] = {2,3,3,3,3,3,3,3,3,3,3,6,6,6,6,6,6,6,6,6,6,6,6,12,12,12,12,12,12,12,13};

__device__ __forceinline__ unsigned short f2bf(float f) {
  unsigned int u = __float_as_uint(f);
  return (unsigned short)((u + 0x7fffu + ((u >> 16) & 1u)) >> 16);
}

// packed f32x2 -> bf16x2 (RNE); no builtin on gfx950 (T12)
__device__ __forceinline__ unsigned int cvt_pk_bf16(float lo, float hi) {
  unsigned int r;
  asm("v_cvt_pk_bf16_f32 %0, %1, %2" : "=v"(r) : "v"(lo), "v"(hi));
  return r;
}

// tanh(x) = 1 - 2/(exp2(2*log2e*x)+1)
__device__ __forceinline__ float fast_tanh(float x) {
  float p = __builtin_amdgcn_exp2f(2.885390082f * x);
  return 1.0f - 2.0f * __builtin_amdgcn_rcpf(p + 1.0f);
}

__device__ __forceinline__ float fast_sigmoid(float x) {
  return __builtin_amdgcn_rcpf(1.0f + __builtin_amdgcn_exp2f(-1.442695041f * x));
}

__device__ __forceinline__ f32x4 mfma_bf16(short8 a, short8 b, f32x4 c) {
  return __builtin_amdgcn_mfma_f32_16x16x32_bf16(
      __builtin_bit_cast(bf16x8, a), __builtin_bit_cast(bf16x8, b), c, 0, 0, 0);
}

// direct global->LDS DMA: 64 lanes x 16B = 1KB per call; LDS dst is
// wave-uniform base (HW adds lane*16), global src is per-lane.
__device__ __forceinline__ void g2lds(const char* gsrc, char* ldst, int lane) {
  __builtin_amdgcn_global_load_lds(
      (const __attribute__((address_space(1))) unsigned int*)(gsrc + lane * 16),
      (__attribute__((address_space(3))) unsigned int*)ldst, 16, 0, 0);
}

// ------------- k_pre: transpose+stats-partials | prep_w1 | prep_w2 ---------
// Stats are PARTIAL sums per (b,t-chunk): plain stores, no atomics, no
// zero-init of poisoned ws; k_gemm reduces the 250 partials inline.
// Transpose reads are float4 (R14: scalar 4B loads -> 1.5 TB/s latency-bound);
// stats recomputed from the bf16 tile (adds ~1e-5 relative rounding, far
// under threshold).
__launch_bounds__(256)
__global__ void k_pre(const float* __restrict__ x,
                      const float* __restrict__ norm_w, const float* __restrict__ norm_b,
                      const float* __restrict__ fc1_w, const float* __restrict__ fc1_b,
                      const float* __restrict__ fc2_w, const float* __restrict__ fc2_b,
                      unsigned short* __restrict__ xtf,
                      float* __restrict__ wsumP, float* __restrict__ wsqP,
                      unsigned short* __restrict__ w1f,
                      float* __restrict__ t1, float* __restrict__ t2,
                      unsigned short* __restrict__ w2f, float* __restrict__ b2) {
  __shared__ unsigned short tile[248 * 128];   // rows staggered by 4f bytes
  __shared__ float sred[256], sqred[256];
  const int bid = blockIdx.x;
  const int tid = threadIdx.x;

  if (bid < 1000) {
    // ---- transpose x[B,C,T,K] -> xtf fragment order + stats partials ----
    const int tc = bid % 250, b = bid / 250;
    const int t0 = tc * 8;
    const float* p = x + ((size_t)b * CDIM * TDIM + t0) * NBANDS;
    // phase 1: float4 loads (992B contiguous per wave-instr), pack bf16 tile
    const int cg = tid >> 6;          // wave id -> c2 range [cg*16, cg*16+16)
    const int f4 = tid & 63;          // 16B chunk of the 248-float t/k span
    if (f4 < 62) {
      const float* pf = p + f4 * 4;
      #pragma unroll 4
      for (int c2i = 0; c2i < 16; ++c2i) {
        const int c2 = cg * 16 + c2i;
        f32x4 va = *(const f32x4*)(pf + (size_t)c2 * 124000);
        f32x4 vb = *(const f32x4*)(pf + (size_t)c2 * 124000 + 62000);
        #pragma unroll
        for (int j = 0; j < 4; ++j) {
          const int f = f4 * 4 + j;
          *(unsigned int*)((char*)tile + f * 256 + ((4 * c2 + 4 * f) & 255)) =
              cvt_pk_bf16(va[j], vb[j]);
        }
      }
    }
    __syncthreads();
    // phase 2: stats from bf16 tile (thread = row f; k = f%31 fixed)
    float s = 0.f, sq = 0.f;
    if (tid < 248) {
      const char* row = (const char*)tile + tid * 256;
      const int st = 4 * tid;
      #pragma unroll 8
      for (int c2 = 0; c2 < 64; ++c2) {
        unsigned int u = *(const unsigned int*)(row + ((4 * c2 + st) & 255));
        float v0 = __uint_as_float(u << 16);
        float v1 = __uint_as_float(u & 0xffff0000u);
        s += v0 + v1;
        sq += v0 * v0 + v1 * v1;
      }
    }
    sred[tid] = s; sqred[tid] = sq;
    __syncthreads();
    if (tid < 31) {
      float ss = 0.f, qs = 0.f;
      #pragma unroll
      for (int j = 0; j < 8; ++j) { ss += sred[tid + 31 * j]; qs += sqred[tid + 31 * j]; }
      wsumP[((size_t)b * 250 + tc) * 31 + tid] = ss;
      wsqP [((size_t)b * 250 + tc) * 31 + tid] = qs;
    }
    for (int idx = tid; idx < 3968; idx += 256) {
      int ti = idx & 7, q4w = (idx >> 3) & 3, kkw = (idx >> 5) & 3, kb = idx >> 7;
      int f = ti * 31 + kb;
      const char* row = (const char*)tile + f * 256;
      const int st = 4 * f;
      u32x4 v;
      #pragma unroll
      for (int j = 0; j < 4; ++j)
        v[j] = *(const unsigned int*)(row + ((kkw * 64 + q4w * 16 + 4 * j + st) & 255));
      int m = b * TDIM + t0 + ti;
      int mtile = m >> 4, mrow = m & 15;
      size_t eoff = ((((size_t)kb * NMTILE + mtile) * 4 + kkw) * 64 + (mrow | (q4w << 4))) * 8;
      *(u32x4*)(xtf + eoff) = v;
    }
  } else if (bid < 1992) {
    // ---- prep fc1: fold norm affine, MFMA-A fragment order (16 rows/blk) --
    const int idx = bid - 1000;
    const int c = tid & 127;
    const int hf2 = tid >> 7;
    #pragma unroll 1
    for (int it = 0; it < 8; ++it) {
      const int kn = idx * 16 + it * 2 + hf2;
      const int k = kn >> 9, n = kn & 511;
      float w  = fc1_w[(size_t)kn * CDIM + c];
      float nw = norm_w[k * CDIM + c];
      float nb = norm_b[k * CDIM + c];
      float wp = w * nw;
      {
        int nc = n >> 7, hh = (n >> 4) & 7, kk = c >> 5;
        int lnw = (n & 15) | (((c >> 3) & 3) << 4);
        size_t eoff = ((((size_t)(k * 4 + nc) * 8 + hh) * 4 + kk) * 64 + lnw) * 8 + (c & 7);
        w1f[eoff] = f2bf(wp);
      }
      float s1 = wp, s2 = w * nb;
      #pragma unroll
      for (int off = 32; off >= 1; off >>= 1) {
        s1 += __shfl_down(s1, off);
        s2 += __shfl_down(s2, off);
      }
      if ((tid & 63) == 0) { sred[tid >> 6] = s1; sqred[tid >> 6] = s2; }
      __syncthreads();
      if ((tid & 127) == 0) {
        t1[kn] = sred[hf2 * 2] + sred[hf2 * 2 + 1];
        t2[kn] = sqred[hf2 * 2] + sqred[hf2 * 2 + 1] + fc1_b[kn];
      }
      __syncthreads();
    }
  } else {
    // ---- prep fc2: GLU-pair permute + pi(k) column permute (8 rows/blk) ---
    // pi(k) = ((k>>2)&1)*16 + (k>>3)*4 + (k&3) so fc1's C-frag feeds fc2's
    // B-frag directly.  o >= 12*bw rows are ZERO (padded staging relies on it).
    const int idx = bid - 1992;
    #pragma unroll 1
    for (int oi = 0; oi < 8; ++oi) {
      const int ko = idx * 8 + oi;
      const int k = ko >> 8;
      const int o = ko & 255;
      const int bw = d_bw[k];
      const int O2 = 12 * bw, hf = 6 * bw;
      const bool valid = o < O2;
      const int srcrow = valid ? ((o & 1) ? (hf + (o >> 1)) : (o >> 1)) : 0;
      const float* sp = fc2_w + ((size_t)k * MAXO + srcrow) * HDIM;
      if (tid == 0 && o < OPAD)
        b2[k * OPAD + o] = valid ? fc2_b[k * MAXO + srcrow] : 0.f;
      const int ot = o >> 4, rr = o & 15;
      for (int j = tid; j < HDIM; j += 256) {
        int ks = j >> 5, hp = j & 31;
        int q  = (hp >> 2) & 3;
        int jj = ((hp >> 4) << 2) | (hp & 3);
        unsigned short val = valid ? f2bf(sp[j]) : (unsigned short)0;
        size_t eoff = (((size_t)(k * 16 + ks)) * 16 + ot) * 512 + (size_t)(rr | (q << 4)) * 8 + jj;
        w2f[eoff] = val;
      }
    }
  }
}

// ------------- fused GEMM: counted-vmcnt pipeline (T3/T4-lite) --------------
// Per chunk: stage(c+1) -> B[(c+1)%3]; asm vmcnt(NST/4) certifies round-c
// landed (each wave issues exactly NST/4 DMAs/round); RAW s_barrier (no
// vmcnt(0) drain); compute(c) from B[c%3].  3 buffers make the
// compute(c) || in-flight-stage(c+1)/issue-stage(c+2) windows WAR-safe.
template<int SMAX, int NST>
__launch_bounds__(256, 2)
__global__ void k_gemm(const unsigned short* __restrict__ xtf,
                       const unsigned short* __restrict__ w1f,
                       const float* __restrict__ t1p, const float* __restrict__ t2p,
                       const unsigned short* __restrict__ w2f,
                       const float* __restrict__ b2p,
                       const float* __restrict__ wsumP, const float* __restrict__ wsqP,
                       float* __restrict__ out, int kbase, int nwg) {
  extern __shared__ char lds[];
  float* const t12 = (float*)lds;              // 4 KB: t1[512] | t2[512]
  char* const B0 = lds + 4096;
  char* const B1 = B0 + NST * 1024;
  char* const B2 = B1 + NST * 1024;
  float* const sstat = (float*)(B2 + NST * 1024);  // own 16B slot (post-B2)
  float* const Ls  = (float*)lds;              // epilogue reuse

  // bijective XCD-aware swizzle
  const int bid = blockIdx.x;
  const int qq = nwg >> 3, r8 = nwg & 7;
  const int xcd = bid & 7, ixd = bid >> 3;
  const int wg = (xcd < r8 ? xcd * (qq + 1) : r8 * (qq + 1) + (xcd - r8) * qq) + ixd;
  const int k = kbase + wg / NMBK;
  const int mb = wg - (k - kbase) * NMBK;
  const int m0 = mb * 128;

  const int tid = threadIdx.x;
  const int lane = tid & 63;
  const int wid = tid >> 6;          // 4 waves, 32 m-rows each
  const int col = lane & 15;
  const int q4 = lane >> 4;

  const int bw = d_bw[k];
  const int nn = d_nn16[k];          // <= SMAX
  const int half = 6 * bw;
  const int boffk = d_boff[k];

  // ---- inline finalize: reduce 250 stats partials for this block's groups --
  const int b0 = m0 / 2000;
  const int b1 = ((m0 + 127 < MTOT) ? (m0 + 127) : (MTOT - 1)) / 2000;
  if (wid <= b1 - b0) {
    const int b = b0 + wid;
    float sP = 0.f, sQ = 0.f;
    for (int t = lane; t < 250; t += 64) {
      sP += wsumP[((size_t)b * 250 + t) * 31 + k];
      sQ += wsqP [((size_t)b * 250 + t) * 31 + k];
    }
    #pragma unroll
    for (int off = 32; off >= 1; off >>= 1) {
      sP += __shfl_down(sP, off);
      sQ += __shfl_down(sQ, off);
    }
    if (lane == 0) {
      const float n = (float)(CDIM * TDIM);
      float mean = sP / n;
      float var = sQ / n - mean * mean;
      sstat[wid * 2] = mean;
      sstat[wid * 2 + 1] = rsqrtf(var + 1e-5f);
    }
  }

  // t1/t2 -> LDS (keeps the main loop free of non-DMA vmem ops)
  #pragma unroll
  for (int i = 0; i < 2; ++i) {
    t12[tid + i * 256] = t1p[k * HDIM + tid + i * 256];
    t12[512 + tid + i * 256] = t2p[k * HDIM + tid + i * 256];
  }

  const char* const w1kc = (const char*)w1f + (size_t)k * 131072;
  const char* const w2kc = (const char*)w2f + (size_t)k * 262144;

  // stage chunk c: 8 w1 tiles + (NST-8) w2 tiles (extras are zero rows)
  auto stage = [&](char* buf, int c) {
    const char* w1c = w1kc + (((c >> 2) * 8 + (c & 3) * 2) * 4096);
    const char* w2c = w2kc + c * 16384;
    #pragma unroll
    for (int i = 0; i < NST / 4; ++i) {
      const int t = wid + i * 4;     // wave-uniform; exactly NST/4 DMAs/wave
      const char* src = (t < 8) ? (w1c + t * 1024) : (w2c + (t - 8) * 1024);
      g2lds(src, buf + t * 1024, lane);
    }
  };
  stage(B0, 0);

  // X fragments in registers for the whole kernel (32 VGPR)
  const int mt0 = (m0 >> 4) + wid * 2;
  short8 xv[2][4];
  #pragma unroll
  for (int r = 0; r < 2; ++r)
    #pragma unroll
    for (int kk = 0; kk < 4; ++kk)
      xv[r][kk] = *(const short8*)(xtf +
          (((size_t)k * NMTILE + mt0 + r) * 4 + kk) * 512 + lane * 8);

  __syncthreads();                   // full drain once: sstat+t12+B0 visible

  float rs[2], rm[2];
  #pragma unroll
  for (int r = 0; r < 2; ++r) {
    int mr = m0 + wid * 32 + r * 16 + col;
    int mc = mr < (MTOT - 1) ? mr : (MTOT - 1);
    int bsel = mc / 2000 - b0;
    rs[r] = sstat[bsel * 2 + 1];
    rm[r] = rs[r] * sstat[bsel * 2];
  }

  const f32x4 fz = {0.f, 0.f, 0.f, 0.f};
  f32x4 acc2[SMAX][2];
  #pragma unroll
  for (int s = 0; s < SMAX; ++s) { acc2[s][0] = fz; acc2[s][1] = fz; }

  char* p0 = B0;
  char* p1 = B1;
  char* p2 = B2;

  #pragma unroll 1
  for (int c = 0; c < 16; ++c) {     // 16 chunks of 32 h
    stage(p1, (c < 15) ? c + 1 : 15);          // uniform DMA count (tail redundant)
    if constexpr (NST == 24) asm volatile("s_waitcnt vmcnt(6)" ::: "memory");
    else if constexpr (NST == 16) asm volatile("s_waitcnt vmcnt(4)" ::: "memory");
    else asm volatile("s_waitcnt vmcnt(3)" ::: "memory");
    __builtin_amdgcn_s_barrier();    // raw: staged loads stay in flight
    __builtin_amdgcn_sched_barrier(0);

    char* const bc = p0;
    // ---- fc1 from LDS ----
    f32x4 a1[2][2];
    a1[0][0] = fz; a1[0][1] = fz; a1[1][0] = fz; a1[1][1] = fz;
    #pragma unroll
    for (int kk = 0; kk < 4; ++kk) {
      short8 wa0 = *(const short8*)(bc + kk * 1024 + lane * 16);
      short8 wa1 = *(const short8*)(bc + 4096 + kk * 1024 + lane * 16);
      #pragma unroll
      for (int r = 0; r < 2; ++r) {
        a1[0][r] = mfma_bf16(wa0, xv[r][kk], a1[0][r]);
        a1[1][r] = mfma_bf16(wa1, xv[r][kk], a1[1][r]);
      }
    }
    // ---- tanh epilogue -> B-frag in-lane (pi(k) order) ----
    short8 hb[2];
    #pragma unroll
    for (int r = 0; r < 2; ++r) {
      u32x4 hbw;
      #pragma unroll
      for (int ht = 0; ht < 2; ++ht) {
        const f32x4 c1 = *(const f32x4*)(t12 + c * 32 + ht * 16 + q4 * 4);
        const f32x4 c2 = *(const f32x4*)(t12 + 512 + c * 32 + ht * 16 + q4 * 4);
        f32x4 v = a1[ht][r];
        float e0 = fast_tanh(fmaf(rs[r], v[0], fmaf(-rm[r], c1[0], c2[0])));
        float e1 = fast_tanh(fmaf(rs[r], v[1], fmaf(-rm[r], c1[1], c2[1])));
        float e2 = fast_tanh(fmaf(rs[r], v[2], fmaf(-rm[r], c1[2], c2[2])));
        float e3 = fast_tanh(fmaf(rs[r], v[3], fmaf(-rm[r], c1[3], c2[3])));
        hbw[ht * 2]     = cvt_pk_bf16(e0, e1);
        hbw[ht * 2 + 1] = cvt_pk_bf16(e2, e3);
      }
      hb[r] = __builtin_bit_cast(short8, hbw);
    }
    // ---- fc2 from LDS (static unroll, wave-uniform guard) ----
    const char* w2l = bc + 8192;
    #pragma unroll
    for (int s = 0; s < SMAX; ++s) {
      if (s < nn) {
        short8 wb = *(const short8*)(w2l + s * 1024 + lane * 16);
        acc2[s][0] = mfma_bf16(wb, hb[0], acc2[s][0]);
        acc2[s][1] = mfma_bf16(wb, hb[1], acc2[s][1]);
      }
    }
    // rotate buffers: read (c+1)%3 next, stage into (c+2)%3
    char* tmp = p0; p0 = p1; p1 = p2; p2 = tmp;
  }

  __syncthreads();                   // full drain before Ls reuse (tail DMAs land)

  // ---- GLU epilogue: pairs (a,g) adjacent in-lane ----
  const float* b2k = b2p + (size_t)k * OPAD;
  const bool plain = (m0 / 2000 == (m0 + 127) / 2000) && (m0 + 128 <= MTOT);
  if (plain) {
    #pragma unroll
    for (int s = 0; s < SMAX; ++s) {
      if (s < nn) {
        f32x4 bias = *(const f32x4*)(b2k + s * 16 + q4 * 4);
        #pragma unroll
        for (int r = 0; r < 2; ++r) {
          const int tloc = wid * 32 + r * 16 + col;
          f32x4 v = acc2[s][r];
          #pragma unroll
          for (int p = 0; p < 2; ++p) {
            float a = v[2 * p] + bias[2 * p];
            float g = v[2 * p + 1] + bias[2 * p + 1];
            int op = s * 8 + q4 * 2 + p;
            if (op < half) {
              int orr = op / 6, occ = op - orr * 6;
              Ls[(orr * 128 + tloc) * 6 + occ] = a * fast_sigmoid(g);
            }
          }
        }
      }
    }
    __syncthreads();
    const int bb = m0 / 2000;
    const int tb = m0 - bb * 2000;
    const size_t obase = ((size_t)bb * 257 + boffk) * 2000;
    const int tot = bw * 384;          // u64 chunks (128 tok * 6 f32 / 2)
    for (int ii = tid; ii < tot; ii += 256) {
      int orr = ii / 384;
      int rem = ii - orr * 384;
      *(unsigned long long*)(out + (obase + (size_t)orr * 2000 + tb) * 6 + rem * 2) =
          *(const unsigned long long*)(Ls + orr * 768 + rem * 2);
    }
  } else {
    // boundary/tail blocks: scatter store
    #pragma unroll
    for (int s = 0; s < SMAX; ++s) {
      if (s < nn) {
        f32x4 bias = *(const f32x4*)(b2k + s * 16 + q4 * 4);
        #pragma unroll
        for (int r = 0; r < 2; ++r) {
          const int m = m0 + wid * 32 + r * 16 + col;
          f32x4 v = acc2[s][r];
          #pragma unroll
          for (int p = 0; p < 2; ++p) {
            float a = v[2 * p] + bias[2 * p];
            float g = v[2 * p + 1] + bias[2 * p + 1];
            int op = s * 8 + q4 * 2 + p;
            if (op < half && m < MTOT) {
              int bbm = m / 2000;
              int t = m - bbm * 2000;
              int orr = op / 6, occ = op - orr * 6;
              out[(((size_t)bbm * 257 + boffk + orr) * TDIM + t) * 6 + occ] =
                  a * fast_sigmoid(g);
            }
          }
        }
      }
    }
  }
}

extern "C" void kernel_launch(void* const* d_in, const int* in_sizes, int n_in,
                              void* d_out, int out_size, void* d_ws, size_t ws_size,
                              hipStream_t stream) {
  const float* x      = (const float*)d_in[0];
  const float* norm_w = (const float*)d_in[1];
  const float* norm_b = (const float*)d_in[2];
  const float* fc1_w  = (const float*)d_in[3];
  const float* fc1_b  = (const float*)d_in[4];
  const float* fc2_w  = (const float*)d_in[5];
  const float* fc2_b  = (const float*)d_in[6];
  float* out = (float*)d_out;
  char* ws = (char*)d_ws;

  size_t off = 0;
  float* wsumP = (float*)(ws + off); off += (size_t)4 * 250 * 31 * 4 + 128;
  float* wsqP  = (float*)(ws + off); off += (size_t)4 * 250 * 31 * 4 + 128;
  unsigned short* xtf = (unsigned short*)(ws + off); off += (size_t)NBANDS * NMTILE * 4 * 512 * 2;
  unsigned short* w1f = (unsigned short*)(ws + off); off += (size_t)NBANDS * 4 * 8 * 4 * 512 * 2;
  float* t1p = (float*)(ws + off); off += (size_t)NBANDS * HDIM * 4;
  float* t2p = (float*)(ws + off); off += (size_t)NBANDS * HDIM * 4;
  unsigned short* w2f = (unsigned short*)(ws + off); off += (size_t)NBANDS * 16 * 16 * 512 * 2;
  float* b2p = (float*)(ws + off); off += (size_t)NBANDS * OPAD * 4;

  // launch 1: transpose+stats-partials | prep_w1 | prep_w2
  hipLaunchKernelGGL(k_pre, dim3(2984), dim3(256), 0, stream,
                     x, norm_w, norm_b, fc1_w, fc1_b, fc2_w, fc2_b,
                     xtf, wsumP, wsqP, w1f, t1p, t2p, w2f, b2p);

  // launches 2-4: class gemms (dyn LDS = 4KB t12 + 3 x NST KB + 128B sstat)
  hipFuncSetAttribute((const void*)k_gemm<13,24>, hipFuncAttributeMaxDynamicSharedMemorySize, 77952);
  hipFuncSetAttribute((const void*)k_gemm<6,16>,  hipFuncAttributeMaxDynamicSharedMemorySize, 53376);
  hipFuncSetAttribute((const void*)k_gemm<3,12>,  hipFuncAttributeMaxDynamicSharedMemorySize, 41088);
  hipLaunchKernelGGL((k_gemm<13,24>), dim3(8 * NMBK),  dim3(256), 77952, stream,
                     xtf, w1f, t1p, t2p, w2f, b2p, wsumP, wsqP, out, 23, 8 * NMBK);
  hipLaunchKernelGGL((k_gemm<6,16>),  dim3(12 * NMBK), dim3(256), 53376, stream,
                     xtf, w1f, t1p, t2p, w2f, b2p, wsumP, wsqP, out, 11, 12 * NMBK);
  hipLaunchKernelGGL((k_gemm<3,12>),  dim3(11 * NMBK), dim3(256), 41088, stream,
                     xtf, w1f, t1p, t2p, w2f, b2p, wsumP, wsqP, out, 0,  11 * NMBK);
}

// Round 16
// 173.619 us; speedup vs baseline: 1.1274x; 1.1274x over previous
//
#include <hip/hip_runtime.h>
#include <hip/hip_bf16.h>

#define NBANDS 31
#define CDIM 128
#define TDIM 2000
#define HDIM 512
#define MTOT 8000
#define MAXO 204
#define OPAD 224       // b2 bias padded length
#define NMTILE 504     // padded 16-row m-tiles per band
#define NMBK 63        // 128-row m-blocks per band

typedef __attribute__((ext_vector_type(8))) short short8;
typedef __attribute__((ext_vector_type(4))) float f32x4;
typedef __attribute__((ext_vector_type(4))) unsigned int u32x4;
typedef __bf16 bf16x8 __attribute__((ext_vector_type(8)));

__constant__ int d_bw[NBANDS]   = {2,3,3,3,3,3,3,3,3,3,3,8,8,8,8,8,8,8,8,8,8,8,8,16,16,16,16,16,16,16,17};
__constant__ int d_boff[NBANDS] = {0,2,5,8,11,14,17,20,23,26,29,32,40,48,56,64,72,80,88,96,104,112,120,128,144,160,176,192,208,224,240};
__constant__ int d_nn16[NBANDS] = {2,3,3,3,3,3,3,3,3,3,3,6,6,6,6,6,6,6,6,6,6,6,6,12,12,12,12,12,12,12,13};

__device__ __forceinline__ unsigned short f2bf(float f) {
  unsigned int u = __float_as_uint(f);
  return (unsigned short)((u + 0x7fffu + ((u >> 16) & 1u)) >> 16);
}

// packed f32x2 -> bf16x2 (RNE); no builtin on gfx950 (T12)
__device__ __forceinline__ unsigned int cvt_pk_bf16(float lo, float hi) {
  unsigned int r;
  asm("v_cvt_pk_bf16_f32 %0, %1, %2" : "=v"(r) : "v"(lo), "v"(hi));
  return r;
}

// tanh(x) = 1 - 2/(exp2(2*log2e*x)+1)
__device__ __forceinline__ float fast_tanh(float x) {
  float p = __builtin_amdgcn_exp2f(2.885390082f * x);
  return 1.0f - 2.0f * __builtin_amdgcn_rcpf(p + 1.0f);
}

__device__ __forceinline__ float fast_sigmoid(float x) {
  return __builtin_amdgcn_rcpf(1.0f + __builtin_amdgcn_exp2f(-1.442695041f * x));
}

__device__ __forceinline__ f32x4 mfma_bf16(short8 a, short8 b, f32x4 c) {
  return __builtin_amdgcn_mfma_f32_16x16x32_bf16(
      __builtin_bit_cast(bf16x8, a), __builtin_bit_cast(bf16x8, b), c, 0, 0, 0);
}

// direct global->LDS DMA: 64 lanes x 16B = 1KB per call; LDS dst is
// wave-uniform base (HW adds lane*16), global src is per-lane.
__device__ __forceinline__ void g2lds(const char* gsrc, char* ldst, int lane) {
  __builtin_amdgcn_global_load_lds(
      (const __attribute__((address_space(1))) unsigned int*)(gsrc + lane * 16),
      (__attribute__((address_space(3))) unsigned int*)ldst, 16, 0, 0);
}

// row stagger for the transpose tile (conflict-free ph1 writes + ph2 reads)
__device__ __forceinline__ int rotf(int f) {
  return ((f >> 2) + ((f & 3) << 3)) & 31;
}

// ------------- k_pre: transpose+stats-partials | prep_w1 | prep_w2 ---------
// R15 lesson: 64KB static tile capped the WHOLE grid at 2 blocks/CU (18%
// occupancy, 90% idle).  Now: dynamic 33KB LDS (tile = 248 x 64 channels,
// transpose split into 2 channel-halves -> 2000 blocks), weight-prep chains
// halved (3968 x 4 / 1984 x 4 blocks) -> 4 blocks/CU, 2x waves, 2x MLP.
// Stats partials: 500 per batch (one per (tc,chalf)), plain stores.
__launch_bounds__(256)
__global__ void k_pre(const float* __restrict__ x,
                      const float* __restrict__ norm_w, const float* __restrict__ norm_b,
                      const float* __restrict__ fc1_w, const float* __restrict__ fc1_b,
                      const float* __restrict__ fc2_w, const float* __restrict__ fc2_b,
                      unsigned short* __restrict__ xtf,
                      float* __restrict__ wsumP, float* __restrict__ wsqP,
                      unsigned short* __restrict__ w1f,
                      float* __restrict__ t1, float* __restrict__ t2,
                      unsigned short* __restrict__ w2f, float* __restrict__ b2) {
  extern __shared__ char lds[];
  unsigned short* const tile = (unsigned short*)lds;     // 248 rows x 128 B
  float* const sred  = (float*)(lds + 31744);            // 256 f
  float* const sqred = (float*)(lds + 32768);            // 256 f
  const int bid = blockIdx.x;
  const int tid = threadIdx.x;

  if (bid < 2000) {
    // ---- transpose x[B,C,T,K] -> xtf fragment order + stats partials ----
    const int chalf = bid & 1;        // channel half: pairs [chalf*32, +32)
    const int bt = bid >> 1;
    const int tc = bt % 250, b = bt / 250;
    const int t0 = tc * 8;
    const float* p = x + ((size_t)b * CDIM * TDIM + t0) * NBANDS;
    // phase 1: float4 loads, pack bf16 into staggered tile (64 channels)
    const int cg = tid >> 6;          // wave -> 8 channel-pairs
    const int f4 = tid & 63;          // 16B chunk of the 248-float t/k span
    if (f4 < 62) {
      const float* pf = p + f4 * 4;
      #pragma unroll
      for (int c2i = 0; c2i < 8; ++c2i) {
        const int c2l = cg * 8 + c2i;               // local pair 0..31
        const size_t cofs = (size_t)(chalf * 32 + c2l) * 124000;
        f32x4 va = *(const f32x4*)(pf + cofs);
        f32x4 vb = *(const f32x4*)(pf + cofs + 62000);
        #pragma unroll
        for (int j = 0; j < 4; ++j) {
          const int f = f4 * 4 + j;
          *(unsigned int*)((char*)tile + f * 128 + ((4 * c2l + 4 * rotf(f)) & 127)) =
              cvt_pk_bf16(va[j], vb[j]);
        }
      }
    }
    __syncthreads();
    // phase 2: stats partial from bf16 tile (thread = row f; k = f%31)
    float s = 0.f, sq = 0.f;
    if (tid < 248) {
      const char* row = (const char*)tile + tid * 128;
      const int st = 4 * rotf(tid);
      #pragma unroll 8
      for (int c2 = 0; c2 < 32; ++c2) {
        unsigned int u = *(const unsigned int*)(row + ((4 * c2 + st) & 127));
        float v0 = __uint_as_float(u << 16);
        float v1 = __uint_as_float(u & 0xffff0000u);
        s += v0 + v1;
        sq += v0 * v0 + v1 * v1;
      }
    }
    sred[tid] = s; sqred[tid] = sq;
    __syncthreads();
    if (tid < 31) {
      float ss = 0.f, qs = 0.f;
      #pragma unroll
      for (int j = 0; j < 8; ++j) { ss += sred[tid + 31 * j]; qs += sqred[tid + 31 * j]; }
      const size_t slot = (size_t)b * 500 + tc * 2 + chalf;
      wsumP[slot * 31 + tid] = ss;
      wsqP [slot * 31 + tid] = qs;
    }
    // phase 3: fragment-order write-out (this block's 2 kkw slices)
    for (int idx = tid; idx < 1984; idx += 256) {
      int ti = idx & 7, q4w = (idx >> 3) & 3, kkl = (idx >> 5) & 1, kb = idx >> 6;
      int f = ti * 31 + kb;
      const char* row = (const char*)tile + f * 128;
      const int st = 4 * rotf(f);
      u32x4 v;
      #pragma unroll
      for (int j = 0; j < 4; ++j)
        v[j] = *(const unsigned int*)(row + ((kkl * 64 + q4w * 16 + 4 * j + st) & 127));
      int m = b * TDIM + t0 + ti;
      int mtile = m >> 4, mrow = m & 15;
      int kkw = chalf * 2 + kkl;
      size_t eoff = ((((size_t)kb * NMTILE + mtile) * 4 + kkw) * 64 + (mrow | (q4w << 4))) * 8;
      *(u32x4*)(xtf + eoff) = v;
    }
  } else if (bid < 5968) {
    // ---- prep fc1: fold norm affine, MFMA-A fragment order (4 rows/blk) ---
    const int idx = bid - 2000;
    const int c = tid & 127;
    const int hf2 = tid >> 7;
    #pragma unroll 1
    for (int it = 0; it < 2; ++it) {
      const int kn = idx * 4 + it * 2 + hf2;
      const int k = kn >> 9, n = kn & 511;
      float w  = fc1_w[(size_t)kn * CDIM + c];
      float nw = norm_w[k * CDIM + c];
      float nb = norm_b[k * CDIM + c];
      float wp = w * nw;
      {
        int nc = n >> 7, hh = (n >> 4) & 7, kk = c >> 5;
        int lnw = (n & 15) | (((c >> 3) & 3) << 4);
        size_t eoff = ((((size_t)(k * 4 + nc) * 8 + hh) * 4 + kk) * 64 + lnw) * 8 + (c & 7);
        w1f[eoff] = f2bf(wp);
      }
      float s1 = wp, s2 = w * nb;
      #pragma unroll
      for (int off = 32; off >= 1; off >>= 1) {
        s1 += __shfl_down(s1, off);
        s2 += __shfl_down(s2, off);
      }
      if ((tid & 63) == 0) { sred[tid >> 6] = s1; sqred[tid >> 6] = s2; }
      __syncthreads();
      if ((tid & 127) == 0) {
        t1[kn] = sred[hf2 * 2] + sred[hf2 * 2 + 1];
        t2[kn] = sqred[hf2 * 2] + sqred[hf2 * 2 + 1] + fc1_b[kn];
      }
      __syncthreads();
    }
  } else {
    // ---- prep fc2: GLU-pair permute + pi(k) column permute (4 rows/blk) ---
    // pi(k) = ((k>>2)&1)*16 + (k>>3)*4 + (k&3) so fc1's C-frag feeds fc2's
    // B-frag directly.  o >= 12*bw rows are ZERO (padded staging relies on it).
    const int idx = bid - 5968;
    #pragma unroll 1
    for (int oi = 0; oi < 4; ++oi) {
      const int ko = idx * 4 + oi;
      const int k = ko >> 8;
      const int o = ko & 255;
      const int bw = d_bw[k];
      const int O2 = 12 * bw, hf = 6 * bw;
      const bool valid = o < O2;
      const int srcrow = valid ? ((o & 1) ? (hf + (o >> 1)) : (o >> 1)) : 0;
      const float* sp = fc2_w + ((size_t)k * MAXO + srcrow) * HDIM;
      if (tid == 0 && o < OPAD)
        b2[k * OPAD + o] = valid ? fc2_b[k * MAXO + srcrow] : 0.f;
      const int ot = o >> 4, rr = o & 15;
      for (int j = tid; j < HDIM; j += 256) {
        int ks = j >> 5, hp = j & 31;
        int q  = (hp >> 2) & 3;
        int jj = ((hp >> 4) << 2) | (hp & 3);
        unsigned short val = valid ? f2bf(sp[j]) : (unsigned short)0;
        size_t eoff = (((size_t)(k * 16 + ks)) * 16 + ot) * 512 + (size_t)(rr | (q << 4)) * 8 + jj;
        w2f[eoff] = val;
      }
    }
  }
}

// ------------- fused GEMM: counted-vmcnt pipeline (T3/T4-lite) --------------
// Per chunk: stage(c+1) -> B[(c+1)%3]; asm vmcnt(NST/4) certifies round-c
// landed; RAW s_barrier (no vmcnt(0) drain); compute(c) from B[c%3].
template<int SMAX, int NST>
__launch_bounds__(256, 2)
__global__ void k_gemm(const unsigned short* __restrict__ xtf,
                       const unsigned short* __restrict__ w1f,
                       const float* __restrict__ t1p, const float* __restrict__ t2p,
                       const unsigned short* __restrict__ w2f,
                       const float* __restrict__ b2p,
                       const float* __restrict__ wsumP, const float* __restrict__ wsqP,
                       float* __restrict__ out, int kbase, int nwg) {
  extern __shared__ char lds[];
  float* const t12 = (float*)lds;              // 4 KB: t1[512] | t2[512]
  char* const B0 = lds + 4096;
  char* const B1 = B0 + NST * 1024;
  char* const B2 = B1 + NST * 1024;
  float* const sstat = (float*)(B2 + NST * 1024);  // own 16B slot (post-B2)
  float* const Ls  = (float*)lds;              // epilogue reuse

  // bijective XCD-aware swizzle
  const int bid = blockIdx.x;
  const int qq = nwg >> 3, r8 = nwg & 7;
  const int xcd = bid & 7, ixd = bid >> 3;
  const int wg = (xcd < r8 ? xcd * (qq + 1) : r8 * (qq + 1) + (xcd - r8) * qq) + ixd;
  const int k = kbase + wg / NMBK;
  const int mb = wg - (k - kbase) * NMBK;
  const int m0 = mb * 128;

  const int tid = threadIdx.x;
  const int lane = tid & 63;
  const int wid = tid >> 6;          // 4 waves, 32 m-rows each
  const int col = lane & 15;
  const int q4 = lane >> 4;

  const int bw = d_bw[k];
  const int nn = d_nn16[k];          // <= SMAX
  const int half = 6 * bw;
  const int boffk = d_boff[k];

  // ---- inline finalize: reduce 500 stats partials for this block's groups --
  const int b0 = m0 / 2000;
  const int b1 = ((m0 + 127 < MTOT) ? (m0 + 127) : (MTOT - 1)) / 2000;
  if (wid <= b1 - b0) {
    const int b = b0 + wid;
    float sP = 0.f, sQ = 0.f;
    for (int t = lane; t < 500; t += 64) {
      sP += wsumP[((size_t)b * 500 + t) * 31 + k];
      sQ += wsqP [((size_t)b * 500 + t) * 31 + k];
    }
    #pragma unroll
    for (int off = 32; off >= 1; off >>= 1) {
      sP += __shfl_down(sP, off);
      sQ += __shfl_down(sQ, off);
    }
    if (lane == 0) {
      const float n = (float)(CDIM * TDIM);
      float mean = sP / n;
      float var = sQ / n - mean * mean;
      sstat[wid * 2] = mean;
      sstat[wid * 2 + 1] = rsqrtf(var + 1e-5f);
    }
  }

  // t1/t2 -> LDS (keeps the main loop free of non-DMA vmem ops)
  #pragma unroll
  for (int i = 0; i < 2; ++i) {
    t12[tid + i * 256] = t1p[k * HDIM + tid + i * 256];
    t12[512 + tid + i * 256] = t2p[k * HDIM + tid + i * 256];
  }

  const char* const w1kc = (const char*)w1f + (size_t)k * 131072;
  const char* const w2kc = (const char*)w2f + (size_t)k * 262144;

  // stage chunk c: 8 w1 tiles + (NST-8) w2 tiles (extras are zero rows)
  auto stage = [&](char* buf, int c) {
    const char* w1c = w1kc + (((c >> 2) * 8 + (c & 3) * 2) * 4096);
    const char* w2c = w2kc + c * 16384;
    #pragma unroll
    for (int i = 0; i < NST / 4; ++i) {
      const int t = wid + i * 4;     // wave-uniform; exactly NST/4 DMAs/wave
      const char* src = (t < 8) ? (w1c + t * 1024) : (w2c + (t - 8) * 1024);
      g2lds(src, buf + t * 1024, lane);
    }
  };
  stage(B0, 0);

  // X fragments in registers for the whole kernel (32 VGPR)
  const int mt0 = (m0 >> 4) + wid * 2;
  short8 xv[2][4];
  #pragma unroll
  for (int r = 0; r < 2; ++r)
    #pragma unroll
    for (int kk = 0; kk < 4; ++kk)
      xv[r][kk] = *(const short8*)(xtf +
          (((size_t)k * NMTILE + mt0 + r) * 4 + kk) * 512 + lane * 8);

  __syncthreads();                   // full drain once: sstat+t12+B0 visible

  float rs[2], rm[2];
  #pragma unroll
  for (int r = 0; r < 2; ++r) {
    int mr = m0 + wid * 32 + r * 16 + col;
    int mc = mr < (MTOT - 1) ? mr : (MTOT - 1);
    int bsel = mc / 2000 - b0;
    rs[r] = sstat[bsel * 2 + 1];
    rm[r] = rs[r] * sstat[bsel * 2];
  }

  const f32x4 fz = {0.f, 0.f, 0.f, 0.f};
  f32x4 acc2[SMAX][2];
  #pragma unroll
  for (int s = 0; s < SMAX; ++s) { acc2[s][0] = fz; acc2[s][1] = fz; }

  char* p0 = B0;
  char* p1 = B1;
  char* p2 = B2;

  #pragma unroll 1
  for (int c = 0; c < 16; ++c) {     // 16 chunks of 32 h
    stage(p1, (c < 15) ? c + 1 : 15);          // uniform DMA count (tail redundant)
    if constexpr (NST == 24) asm volatile("s_waitcnt vmcnt(6)" ::: "memory");
    else if constexpr (NST == 16) asm volatile("s_waitcnt vmcnt(4)" ::: "memory");
    else asm volatile("s_waitcnt vmcnt(3)" ::: "memory");
    __builtin_amdgcn_s_barrier();    // raw: staged loads stay in flight
    __builtin_amdgcn_sched_barrier(0);

    char* const bc = p0;
    // ---- fc1 from LDS ----
    f32x4 a1[2][2];
    a1[0][0] = fz; a1[0][1] = fz; a1[1][0] = fz; a1[1][1] = fz;
    #pragma unroll
    for (int kk = 0; kk < 4; ++kk) {
      short8 wa0 = *(const short8*)(bc + kk * 1024 + lane * 16);
      short8 wa1 = *(const short8*)(bc + 4096 + kk * 1024 + lane * 16);
      #pragma unroll
      for (int r = 0; r < 2; ++r) {
        a1[0][r] = mfma_bf16(wa0, xv[r][kk], a1[0][r]);
        a1[1][r] = mfma_bf16(wa1, xv[r][kk], a1[1][r]);
      }
    }
    // ---- tanh epilogue -> B-frag in-lane (pi(k) order) ----
    short8 hb[2];
    #pragma unroll
    for (int r = 0; r < 2; ++r) {
      u32x4 hbw;
      #pragma unroll
      for (int ht = 0; ht < 2; ++ht) {
        const f32x4 c1 = *(const f32x4*)(t12 + c * 32 + ht * 16 + q4 * 4);
        const f32x4 c2 = *(const f32x4*)(t12 + 512 + c * 32 + ht * 16 + q4 * 4);
        f32x4 v = a1[ht][r];
        float e0 = fast_tanh(fmaf(rs[r], v[0], fmaf(-rm[r], c1[0], c2[0])));
        float e1 = fast_tanh(fmaf(rs[r], v[1], fmaf(-rm[r], c1[1], c2[1])));
        float e2 = fast_tanh(fmaf(rs[r], v[2], fmaf(-rm[r], c1[2], c2[2])));
        float e3 = fast_tanh(fmaf(rs[r], v[3], fmaf(-rm[r], c1[3], c2[3])));
        hbw[ht * 2]     = cvt_pk_bf16(e0, e1);
        hbw[ht * 2 + 1] = cvt_pk_bf16(e2, e3);
      }
      hb[r] = __builtin_bit_cast(short8, hbw);
    }
    // ---- fc2 from LDS (static unroll, wave-uniform guard) ----
    const char* w2l = bc + 8192;
    #pragma unroll
    for (int s = 0; s < SMAX; ++s) {
      if (s < nn) {
        short8 wb = *(const short8*)(w2l + s * 1024 + lane * 16);
        acc2[s][0] = mfma_bf16(wb, hb[0], acc2[s][0]);
        acc2[s][1] = mfma_bf16(wb, hb[1], acc2[s][1]);
      }
    }
    // rotate buffers: read (c+1)%3 next, stage into (c+2)%3
    char* tmp = p0; p0 = p1; p1 = p2; p2 = tmp;
  }

  __syncthreads();                   // full drain before Ls reuse (tail DMAs land)

  // ---- GLU epilogue: pairs (a,g) adjacent in-lane ----
  const float* b2k = b2p + (size_t)k * OPAD;
  const bool plain = (m0 / 2000 == (m0 + 127) / 2000) && (m0 + 128 <= MTOT);
  if (plain) {
    #pragma unroll
    for (int s = 0; s < SMAX; ++s) {
      if (s < nn) {
        f32x4 bias = *(const f32x4*)(b2k + s * 16 + q4 * 4);
        #pragma unroll
        for (int r = 0; r < 2; ++r) {
          const int tloc = wid * 32 + r * 16 + col;
          f32x4 v = acc2[s][r];
          #pragma unroll
          for (int p = 0; p < 2; ++p) {
            float a = v[2 * p] + bias[2 * p];
            float g = v[2 * p + 1] + bias[2 * p + 1];
            int op = s * 8 + q4 * 2 + p;
            if (op < half) {
              int orr = op / 6, occ = op - orr * 6;
              Ls[(orr * 128 + tloc) * 6 + occ] = a * fast_sigmoid(g);
            }
          }
        }
      }
    }
    __syncthreads();
    const int bb = m0 / 2000;
    const int tb = m0 - bb * 2000;
    const size_t obase = ((size_t)bb * 257 + boffk) * 2000;
    const int tot = bw * 384;          // u64 chunks (128 tok * 6 f32 / 2)
    for (int ii = tid; ii < tot; ii += 256) {
      int orr = ii / 384;
      int rem = ii - orr * 384;
      *(unsigned long long*)(out + (obase + (size_t)orr * 2000 + tb) * 6 + rem * 2) =
          *(const unsigned long long*)(Ls + orr * 768 + rem * 2);
    }
  } else {
    // boundary/tail blocks: scatter store
    #pragma unroll
    for (int s = 0; s < SMAX; ++s) {
      if (s < nn) {
        f32x4 bias = *(const f32x4*)(b2k + s * 16 + q4 * 4);
        #pragma unroll
        for (int r = 0; r < 2; ++r) {
          const int m = m0 + wid * 32 + r * 16 + col;
          f32x4 v = acc2[s][r];
          #pragma unroll
          for (int p = 0; p < 2; ++p) {
            float a = v[2 * p] + bias[2 * p];
            float g = v[2 * p + 1] + bias[2 * p + 1];
            int op = s * 8 + q4 * 2 + p;
            if (op < half && m < MTOT) {
              int bbm = m / 2000;
              int t = m - bbm * 2000;
              int orr = op / 6, occ = op - orr * 6;
              out[(((size_t)bbm * 257 + boffk + orr) * TDIM + t) * 6 + occ] =
                  a * fast_sigmoid(g);
            }
          }
        }
      }
    }
  }
}

extern "C" void kernel_launch(void* const* d_in, const int* in_sizes, int n_in,
                              void* d_out, int out_size, void* d_ws, size_t ws_size,
                              hipStream_t stream) {
  const float* x      = (const float*)d_in[0];
  const float* norm_w = (const float*)d_in[1];
  const float* norm_b = (const float*)d_in[2];
  const float* fc1_w  = (const float*)d_in[3];
  const float* fc1_b  = (const float*)d_in[4];
  const float* fc2_w  = (const float*)d_in[5];
  const float* fc2_b  = (const float*)d_in[6];
  float* out = (float*)d_out;
  char* ws = (char*)d_ws;

  size_t off = 0;
  float* wsumP = (float*)(ws + off); off += (size_t)4 * 500 * 31 * 4 + 128;
  float* wsqP  = (float*)(ws + off); off += (size_t)4 * 500 * 31 * 4 + 128;
  unsigned short* xtf = (unsigned short*)(ws + off); off += (size_t)NBANDS * NMTILE * 4 * 512 * 2;
  unsigned short* w1f = (unsigned short*)(ws + off); off += (size_t)NBANDS * 4 * 8 * 4 * 512 * 2;
  float* t1p = (float*)(ws + off); off += (size_t)NBANDS * HDIM * 4;
  float* t2p = (float*)(ws + off); off += (size_t)NBANDS * HDIM * 4;
  unsigned short* w2f = (unsigned short*)(ws + off); off += (size_t)NBANDS * 16 * 16 * 512 * 2;
  float* b2p = (float*)(ws + off); off += (size_t)NBANDS * OPAD * 4;

  // launch 1: transpose (2000 blk) | prep_w1 (3968 blk) | prep_w2 (1984 blk)
  hipFuncSetAttribute((const void*)k_pre, hipFuncAttributeMaxDynamicSharedMemorySize, 33792);
  hipLaunchKernelGGL(k_pre, dim3(7952), dim3(256), 33792, stream,
                     x, norm_w, norm_b, fc1_w, fc1_b, fc2_w, fc2_b,
                     xtf, wsumP, wsqP, w1f, t1p, t2p, w2f, b2p);

  // launches 2-4: class gemms (dyn LDS = 4KB t12 + 3 x NST KB + 128B sstat)
  hipFuncSetAttribute((const void*)k_gemm<13,24>, hipFuncAttributeMaxDynamicSharedMemorySize, 77952);
  hipFuncSetAttribute((const void*)k_gemm<6,16>,  hipFuncAttributeMaxDynamicSharedMemorySize, 53376);
  hipFuncSetAttribute((const void*)k_gemm<3,12>,  hipFuncAttributeMaxDynamicSharedMemorySize, 41088);
  hipLaunchKernelGGL((k_gemm<13,24>), dim3(8 * NMBK),  dim3(256), 77952, stream,
                     xtf, w1f, t1p, t2p, w2f, b2p, wsumP, wsqP, out, 23, 8 * NMBK);
  hipLaunchKernelGGL((k_gemm<6,16>),  dim3(12 * NMBK), dim3(256), 53376, stream,
                     xtf, w1f, t1p, t2p, w2f, b2p, wsumP, wsqP, out, 11, 12 * NMBK);
  hipLaunchKernelGGL((k_gemm<3,12>),  dim3(11 * NMBK), dim3(256), 41088, stream,
                     xtf, w1f, t1p, t2p, w2f, b2p, wsumP, wsqP, out, 0,  11 * NMBK);
}